// Round 11
// baseline (197.262 us; speedup 1.0000x reference)
//
#include <hip/hip_runtime.h>

#define N_NODES 100000
#define N_EDGES 3200000

// ---- bucket parameters -----------------------------------------------------
#define BSH   8                    // log2(nodes per bucket)
#define BSZ   256                  // nodes per bucket
#define NB    391                  // ceil(N_NODES / BSZ)
#define CAP   10560                // per-bucket capacity (multiple of 8)
#define CHUNK 8192                 // edges per binning block
#define BINT  1024                 // threads per binning block
#define EPT   (CHUNK / BINT)       // 8 edges per thread
#define GT    256                  // threads per gather-slice block
#define SPLIT 4                    // slices per bucket
#define TRASH 256u                 // local slot 256 = discard
#define NM1   ((unsigned)(N_NODES - 1))

// ---------------------------------------------------------------------------
// Algebra (x is [N,1]):
//   p[u]   = dinv[u] * x[u]
//   s[v]   = dinv[v] * (sum_in p[u] + dinv[v]*x[v])
//   t[v]   = relu(s[v]*W1 + b1) @ W2          (2-vector)
//   q[v]   = dinv[v] * t[v]
//   out[v] = dinv[v] * (sum_in q[u] + q[v]) + b2
//
// R4:  device f32 atomics are memory-side (32B txn, ~20 G/s) -> gather.
// R6:  scattered 4B binning writes -> 5x write amp -> LDS counting sort.
// R9:  gathers parallelism-starved -> slice split + merge.
// R10: a-kernels latency-bound at VALUBusy 2% (serial dep chain/thread).
//      Fix: uint4 x4 entry batching (4x MLP), q-payload trick (1 random
//      load in k4a instead of 2).
// Entry: (src << 9) | local; local in [0,255] real, 256 = TRASH pad.
// ---------------------------------------------------------------------------

__global__ void k0_zero(unsigned* __restrict__ cursor) {
    int i = blockIdx.x * blockDim.x + threadIdx.x;
    if (i < NB) cursor[i] = 0u;
}

__global__ __launch_bounds__(BINT) void
k1_bin(const int* __restrict__ src, const int* __restrict__ dst,
       unsigned* __restrict__ cursor, unsigned* __restrict__ binned, int ne) {
    __shared__ unsigned hist[NB];      // per-bucket count (rank source)
    __shared__ unsigned basel[NB];     // exclusive prefix into sorted[]
    __shared__ unsigned gbase[NB];     // global segment base per bucket
    __shared__ unsigned pcnt[NB];      // padded count per bucket
    __shared__ unsigned sorted[CHUNK]; // bucket-sorted entries
    __shared__ unsigned scan[BINT];    // scan workspace
    const int tid = threadIdx.x;
    const int b0  = blockIdx.x * CHUNK;
    const int end = min(b0 + CHUNK, ne);

    for (int i = tid; i < NB; i += BINT) hist[i] = 0u;
    __syncthreads();

    // read edges once, take rank within (block, bucket)
    unsigned ent[EPT], ebr[EPT];
#pragma unroll
    for (int k = 0; k < EPT; ++k) {
        int i = b0 + tid + k * BINT;
        ent[k] = 0xFFFFFFFFu;
        if (i < end) {
            unsigned v = (unsigned)dst[i];
            unsigned u = (unsigned)src[i];
            unsigned b = v >> BSH;
            unsigned r = atomicAdd(&hist[b], 1u);
            ent[k] = (u << 9) | (v & (BSZ - 1u));
            ebr[k] = (b << 16) | r;            // b<391 (9b), r<8192 (13b)
        }
    }
    __syncthreads();

    // exclusive block scan of hist -> basel (NB=391 <= BINT)
    unsigned v0 = (tid < NB) ? hist[tid] : 0u;
    scan[tid] = v0;
    __syncthreads();
    for (int off = 1; off < BINT; off <<= 1) {
        unsigned mine = scan[tid];
        unsigned add  = (tid >= off) ? scan[tid - off] : 0u;
        __syncthreads();
        scan[tid] = mine + add;
        __syncthreads();
    }
    if (tid < NB) basel[tid] = scan[tid] - v0;
    __syncthreads();

    // place into LDS sorted buffer
#pragma unroll
    for (int k = 0; k < EPT; ++k) {
        if (ent[k] != 0xFFFFFFFFu)
            sorted[basel[ebr[k] >> 16] + (ebr[k] & 0xFFFFu)] = ent[k];
    }

    // reserve 8-aligned (32 B) global segments
    if (tid < NB) {
        unsigned c = hist[tid];
        unsigned p = (c + 7u) & ~7u;
        pcnt[tid]  = p;
        gbase[tid] = p ? atomicAdd(&cursor[tid], p) : 0u;
    }
    __syncthreads();

    // copy out: wave w handles buckets w, w+16, ... (full-sector stores)
    const int wave = tid >> 6, lane = tid & 63;
    for (int b = wave; b < NB; b += BINT / 64) {
        unsigned c = hist[b], p = pcnt[b], gb = gbase[b], lb = basel[b];
        if (p == 0u || gb + p > CAP) continue;   // overflow guard (never real)
        unsigned* dstp = binned + (size_t)b * CAP + gb;
        for (unsigned j = lane; j < p; j += 64)
            dstp[j] = (j < c) ? sorted[lb + j] : TRASH;
    }
}

// ---- slice gather kernels: grid = NB*SPLIT, uint4-batched ------------------

// degree counts per slice -> partc[b][slice][256]
__global__ __launch_bounds__(GT) void
k2a_deg(const unsigned* __restrict__ binned, const unsigned* __restrict__ cursor,
        unsigned* __restrict__ partc) {
    __shared__ unsigned cnt[BSZ + 1];
    const int b = blockIdx.x >> 2, sl = blockIdx.x & 3, tid = threadIdx.x;
    if (tid < GT) { cnt[tid] = 0u; if (tid == 0) cnt[BSZ] = 0u; }
    __syncthreads();
    unsigned m = cursor[b]; if (m > CAP) m = 0u;   // replay-safe
    const uint4* eb4 = (const uint4*)(binned + (size_t)b * CAP);
    unsigned m4 = m >> 2;                           // m is a multiple of 8
    for (unsigned j = sl * GT + tid; j < m4; j += GT * SPLIT) {
        uint4 e = eb4[j];
        atomicAdd(&cnt[min(e.x & 511u, TRASH)], 1u);
        atomicAdd(&cnt[min(e.y & 511u, TRASH)], 1u);
        atomicAdd(&cnt[min(e.z & 511u, TRASH)], 1u);
        atomicAdd(&cnt[min(e.w & 511u, TRASH)], 1u);
    }
    __syncthreads();
    if (tid < GT)
        partc[((size_t)b * SPLIT + sl) * BSZ + tid] = cnt[tid];
}

// merge counts -> dinv, p   (grid over nodes)
__global__ __launch_bounds__(512) void
k2b_dinv(const unsigned* __restrict__ partc, const float* __restrict__ x,
         float* __restrict__ dinv, float* __restrict__ p) {
    int g = blockIdx.x * 512 + threadIdx.x;
    if (g < N_NODES) {
        int b = g >> 8, l = g & 255;
        const unsigned* pc = partc + (size_t)b * SPLIT * BSZ + l;
        unsigned deg = 1u + pc[0] + pc[BSZ] + pc[2 * BSZ] + pc[3 * BSZ];
        float di = rsqrtf((float)deg);
        dinv[g] = di;
        p[g] = di * x[g];
    }
}

// layer-1 sums per slice -> parts[b][slice][256]
__global__ __launch_bounds__(GT) void
k3a_sum(const unsigned* __restrict__ binned, const unsigned* __restrict__ cursor,
        const float* __restrict__ p, float* __restrict__ parts) {
    __shared__ float acc[BSZ + 1];
    const int b = blockIdx.x >> 2, sl = blockIdx.x & 3, tid = threadIdx.x;
    if (tid < GT) { acc[tid] = 0.0f; if (tid == 0) acc[BSZ] = 0.0f; }
    __syncthreads();
    unsigned m = cursor[b]; if (m > CAP) m = 0u;   // replay-safe
    const uint4* eb4 = (const uint4*)(binned + (size_t)b * CAP);
    unsigned m4 = m >> 2;
    for (unsigned j = sl * GT + tid; j < m4; j += GT * SPLIT) {
        uint4 e = eb4[j];
        float p0 = p[min(e.x >> 9, NM1)];
        float p1 = p[min(e.y >> 9, NM1)];
        float p2 = p[min(e.z >> 9, NM1)];
        float p3 = p[min(e.w >> 9, NM1)];
        atomicAdd(&acc[min(e.x & 511u, TRASH)], p0);
        atomicAdd(&acc[min(e.y & 511u, TRASH)], p1);
        atomicAdd(&acc[min(e.z & 511u, TRASH)], p2);
        atomicAdd(&acc[min(e.w & 511u, TRASH)], p3);
    }
    __syncthreads();
    if (tid < GT)
        parts[((size_t)b * SPLIT + sl) * BSZ + tid] = acc[tid];
}

// merge sums -> s -> tiny MLP -> q = dinv * t   (grid over nodes)
__global__ __launch_bounds__(512) void
k3b_mlp(const float* __restrict__ parts, const float* __restrict__ x,
        const float* __restrict__ dinv,
        const float* __restrict__ W1, const float* __restrict__ b1,
        const float* __restrict__ W2, float* __restrict__ q) {
    int g = blockIdx.x * 512 + threadIdx.x;
    if (g < N_NODES) {
        int b = g >> 8, l = g & 255;
        const float* ps = parts + (size_t)b * SPLIT * BSZ + l;
        float sum = ps[0] + ps[BSZ] + ps[2 * BSZ] + ps[3 * BSZ];
        float di = dinv[g];
        float s = di * (sum + di * x[g]);
        float t0 = 0.0f, t1 = 0.0f;
#pragma unroll
        for (int k = 0; k < 16; ++k) {
            float h = fmaxf(fmaf(s, W1[k], b1[k]), 0.0f);
            t0 = fmaf(h, W2[2 * k], t0);
            t1 = fmaf(h, W2[2 * k + 1], t1);
        }
        q[2 * g]     = di * t0;
        q[2 * g + 1] = di * t1;
    }
}

// layer-2 sums per slice -> (part0, part1)[b][slice][256]
__global__ __launch_bounds__(GT) void
k4a_sum(const unsigned* __restrict__ binned, const unsigned* __restrict__ cursor,
        const float* __restrict__ q, float* __restrict__ part0,
        float* __restrict__ part1) {
    __shared__ float a0[BSZ + 1], a1[BSZ + 1];
    const int b = blockIdx.x >> 2, sl = blockIdx.x & 3, tid = threadIdx.x;
    if (tid < GT) { a0[tid] = 0.0f; a1[tid] = 0.0f;
                    if (tid == 0) { a0[BSZ] = 0.0f; a1[BSZ] = 0.0f; } }
    __syncthreads();
    unsigned m = cursor[b]; if (m > CAP) m = 0u;   // replay-safe
    const uint4* eb4 = (const uint4*)(binned + (size_t)b * CAP);
    const float2* __restrict__ q2 = (const float2*)q;
    unsigned m4 = m >> 2;
    for (unsigned j = sl * GT + tid; j < m4; j += GT * SPLIT) {
        uint4 e = eb4[j];
        float2 q0 = q2[min(e.x >> 9, NM1)];
        float2 q1 = q2[min(e.y >> 9, NM1)];
        float2 qq2 = q2[min(e.z >> 9, NM1)];
        float2 q3 = q2[min(e.w >> 9, NM1)];
        unsigned l0 = min(e.x & 511u, TRASH), l1 = min(e.y & 511u, TRASH);
        unsigned l2 = min(e.z & 511u, TRASH), l3 = min(e.w & 511u, TRASH);
        atomicAdd(&a0[l0], q0.x); atomicAdd(&a1[l0], q0.y);
        atomicAdd(&a0[l1], q1.x); atomicAdd(&a1[l1], q1.y);
        atomicAdd(&a0[l2], qq2.x); atomicAdd(&a1[l2], qq2.y);
        atomicAdd(&a0[l3], q3.x); atomicAdd(&a1[l3], q3.y);
    }
    __syncthreads();
    if (tid < GT) {
        size_t o = ((size_t)b * SPLIT + sl) * BSZ + tid;
        part0[o] = a0[tid];
        part1[o] = a1[tid];
    }
}

// merge layer-2 sums -> out   (grid over nodes)
__global__ __launch_bounds__(512) void
k4b_out(const float* __restrict__ part0, const float* __restrict__ part1,
        const float* __restrict__ dinv, const float* __restrict__ q,
        const float* __restrict__ b2, float* __restrict__ out) {
    int g = blockIdx.x * 512 + threadIdx.x;
    if (g < N_NODES) {
        int b = g >> 8, l = g & 255;
        const float* p0 = part0 + (size_t)b * SPLIT * BSZ + l;
        const float* p1 = part1 + (size_t)b * SPLIT * BSZ + l;
        float o0 = p0[0] + p0[BSZ] + p0[2 * BSZ] + p0[3 * BSZ];
        float o1 = p1[0] + p1[BSZ] + p1[2 * BSZ] + p1[3 * BSZ];
        float di = dinv[g];
        float2 o;
        o.x = fmaf(di, o0 + q[2 * g],     b2[0]);
        o.y = fmaf(di, o1 + q[2 * g + 1], b2[1]);
        ((float2*)out)[g] = o;
    }
}

// ---- legacy atomic-scatter path (fallback if ws too small) -----------------
__global__ void k_init_deg(unsigned* __restrict__ degc, int n) {
    int i = blockIdx.x * blockDim.x + threadIdx.x;
    if (i < n) degc[i] = 1u;
}
__global__ void k_count_deg(const int* __restrict__ dst, unsigned* __restrict__ degc, int ne) {
    int stride = gridDim.x * blockDim.x;
    for (int i = blockIdx.x * blockDim.x + threadIdx.x; i < ne; i += stride)
        atomicAdd(&degc[dst[i]], 1u);
}
__global__ void k_dinv_selfloop(const float* __restrict__ x, const unsigned* __restrict__ degc,
                                float* __restrict__ dinv, float* __restrict__ s, int n) {
    int i = blockIdx.x * blockDim.x + threadIdx.x;
    if (i < n) {
        float di = rsqrtf((float)degc[i]);
        dinv[i] = di;
        s[i] = di * di * x[i];
    }
}
__global__ void k_scatter_s(const int* __restrict__ src, const int* __restrict__ dst,
                            const float* __restrict__ x, const float* __restrict__ dinv,
                            float* __restrict__ s, int ne) {
    int stride = gridDim.x * blockDim.x;
    for (int i = blockIdx.x * blockDim.x + threadIdx.x; i < ne; i += stride) {
        int u = src[i], v = dst[i];
        unsafeAtomicAdd(&s[v], dinv[u] * dinv[v] * x[u]);
    }
}
__global__ void k_node_g(const float* __restrict__ s, const float* __restrict__ dinv,
                         const float* __restrict__ W1, const float* __restrict__ b1,
                         const float* __restrict__ W2, const float* __restrict__ b2,
                         float* __restrict__ t, float* __restrict__ out, int n) {
    int i = blockIdx.x * blockDim.x + threadIdx.x;
    if (i < n) {
        float si = s[i];
        float t0 = 0.0f, t1 = 0.0f;
#pragma unroll
        for (int k = 0; k < 16; ++k) {
            float h = fmaxf(fmaf(si, W1[k], b1[k]), 0.0f);
            t0 = fmaf(h, W2[2 * k], t0);
            t1 = fmaf(h, W2[2 * k + 1], t1);
        }
        t[2 * i] = t0; t[2 * i + 1] = t1;
        float d2 = dinv[i] * dinv[i];
        out[2 * i]     = fmaf(d2, t0, b2[0]);
        out[2 * i + 1] = fmaf(d2, t1, b2[1]);
    }
}
__global__ void k_scatter_out(const int* __restrict__ src, const int* __restrict__ dst,
                              const float* __restrict__ dinv, const float* __restrict__ t,
                              float* __restrict__ out, int ne) {
    int stride = gridDim.x * blockDim.x;
    const float2* __restrict__ t2 = (const float2*)t;
    for (int i = blockIdx.x * blockDim.x + threadIdx.x; i < ne; i += stride) {
        int u = src[i], v = dst[i];
        float nrm = dinv[u] * dinv[v];
        float2 tu = t2[u];
        unsafeAtomicAdd(&out[2 * v],     nrm * tu.x);
        unsafeAtomicAdd(&out[2 * v + 1], nrm * tu.y);
    }
}

extern "C" void kernel_launch(void* const* d_in, const int* in_sizes, int n_in,
                              void* d_out, int out_size, void* d_ws, size_t ws_size,
                              hipStream_t stream) {
    const float* x  = (const float*)d_in[0];
    const int*   ei = (const int*)d_in[1];   // int32 [2, E]
    const float* W1 = (const float*)d_in[2];
    const float* b1 = (const float*)d_in[3];
    const float* W2 = (const float*)d_in[4];
    const float* b2 = (const float*)d_in[5];
    float*       out = (float*)d_out;

    const int* src = ei;
    const int* dst = ei + N_EDGES;

    // ws layout (4B units):
    // cursor[512] | dinv[N] | p[N] | q[2N] | bufA[NB*4*256] | bufB[NB*4*256] | binned[NB*CAP]
    float* base = (float*)d_ws;
    unsigned* cursor = (unsigned*)d_ws;
    float* dinv = base + 512;
    float* p    = base + 512 + N_NODES;
    float* q    = base + 512 + 2 * N_NODES;
    float* bufA = base + 512 + 4 * N_NODES;
    float* bufB = bufA + (size_t)NB * SPLIT * BSZ;
    unsigned* binned = (unsigned*)(bufB + (size_t)NB * SPLIT * BSZ);
    const size_t NEEDED = ((size_t)512 + 4 * N_NODES + 2 * (size_t)NB * SPLIT * BSZ
                           + (size_t)NB * CAP) * 4;              // ~21.3 MB

    if (ws_size >= NEEDED) {
        const int nbin_blocks = (N_EDGES + CHUNK - 1) / CHUNK;   // 391
        const int node_grid = (N_NODES + 511) / 512;             // 196
        k0_zero<<<2, 256, 0, stream>>>(cursor);
        k1_bin<<<nbin_blocks, BINT, 0, stream>>>(src, dst, cursor, binned, N_EDGES);
        k2a_deg<<<NB * SPLIT, GT, 0, stream>>>(binned, cursor, (unsigned*)bufA);
        k2b_dinv<<<node_grid, 512, 0, stream>>>((unsigned*)bufA, x, dinv, p);
        k3a_sum<<<NB * SPLIT, GT, 0, stream>>>(binned, cursor, p, bufA);
        k3b_mlp<<<node_grid, 512, 0, stream>>>(bufA, x, dinv, W1, b1, W2, q);
        k4a_sum<<<NB * SPLIT, GT, 0, stream>>>(binned, cursor, q, bufA, bufB);
        k4b_out<<<node_grid, 512, 0, stream>>>(bufA, bufB, dinv, q, b2, out);
    } else {
        // legacy atomic-scatter path
        unsigned* degc = (unsigned*)d_ws;
        float* ldinv = base + N_NODES;
        float* s     = base + 2 * N_NODES;
        float* t     = base + 3 * N_NODES;
        const int BLK = 256;
        const int node_grid = (N_NODES + BLK - 1) / BLK;
        const int edge_grid = 2048;
        k_init_deg<<<node_grid, BLK, 0, stream>>>(degc, N_NODES);
        k_count_deg<<<edge_grid, BLK, 0, stream>>>(dst, degc, N_EDGES);
        k_dinv_selfloop<<<node_grid, BLK, 0, stream>>>(x, degc, ldinv, s, N_NODES);
        k_scatter_s<<<edge_grid, BLK, 0, stream>>>(src, dst, x, ldinv, s, N_EDGES);
        k_node_g<<<node_grid, BLK, 0, stream>>>(s, ldinv, W1, b1, W2, b2, t, out, N_NODES);
        k_scatter_out<<<edge_grid, BLK, 0, stream>>>(src, dst, ldinv, t, out, N_EDGES);
    }
}

// Round 13
// 152.808 us; speedup vs baseline: 1.2909x; 1.2909x over previous
//
#include <hip/hip_runtime.h>

#define N_NODES 100000
#define N_EDGES 3200000

// ---- bucket parameters -----------------------------------------------------
#define BSH   8                    // log2(nodes per bucket)
#define BSZ   256                  // nodes per bucket
#define NB    391                  // ceil(N_NODES / BSZ)
#define CAP   10560                // per-bucket capacity (mult of 8; <= 11*1024)
#define CHUNK 8192                 // edges per binning block
#define BINT  1024                 // threads per binning block
#define EPT   (CHUNK / BINT)       // 8 edges per thread
#define ST    1024                 // threads per sort block
#define SIT   11                   // ceil(CAP / ST) load slots per sort thread
#define GBT   128                  // threads per gather block (2 waves)
#define TRASH 256u                 // local slot 256 = discard
#define NM1   ((unsigned)(N_NODES - 1))
#define OSTR  257                  // offs stride per bucket (l=0..256)

// ---------------------------------------------------------------------------
// Algebra (x is [N,1]):
//   p[u]   = dinv[u] * x[u]
//   s[v]   = dinv[v] * (sum_in p[u] + dinv[v]*x[v])
//   t[v]   = relu(s[v]*W1 + b1) @ W2          (2-vector)
//   q[v]   = dinv[v] * t[v]
//   out[v] = dinv[v] * (sum_in q[u] + q[v]) + b2
//
// R4:  device f32 atomics are memory-side (~20 G/s) -> gather, not scatter.
// R6:  scattered 4B binning writes -> 5x write amp -> LDS counting sort in k1.
// R9-R11: bucket-gather passes with LDS atomics are latency-bound (~55us
//      invariant to occupancy/ILP knobs). Fix: second-level in-place LDS sort
//      by local node (k15) -> degree comes free from its histogram, gathers
//      become atomic-free contiguous run-scans with register accumulation.
// binned after k1: (src<<9)|local with TRASH pads; after k15: pure src,
// runs delimited by offs[b][l], pads compacted to segment tail.
// ---------------------------------------------------------------------------

__global__ void k0_zero(unsigned* __restrict__ cursor) {
    int i = blockIdx.x * blockDim.x + threadIdx.x;
    if (i < NB) cursor[i] = 0u;
}

__global__ __launch_bounds__(BINT) void
k1_bin(const int* __restrict__ src, const int* __restrict__ dst,
       unsigned* __restrict__ cursor, unsigned* __restrict__ binned, int ne) {
    __shared__ unsigned hist[NB];      // per-bucket count (rank source)
    __shared__ unsigned basel[NB];     // exclusive prefix into sorted[]
    __shared__ unsigned gbase[NB];     // global segment base per bucket
    __shared__ unsigned pcnt[NB];      // padded count per bucket
    __shared__ unsigned sorted[CHUNK]; // bucket-sorted entries
    __shared__ unsigned scan[BINT];    // scan workspace
    const int tid = threadIdx.x;
    const int b0  = blockIdx.x * CHUNK;
    const int end = min(b0 + CHUNK, ne);

    for (int i = tid; i < NB; i += BINT) hist[i] = 0u;
    __syncthreads();

    unsigned ent[EPT], ebr[EPT];
#pragma unroll
    for (int k = 0; k < EPT; ++k) {
        int i = b0 + tid + k * BINT;
        ent[k] = 0xFFFFFFFFu;
        if (i < end) {
            unsigned v = (unsigned)dst[i];
            unsigned u = (unsigned)src[i];
            unsigned b = v >> BSH;
            unsigned r = atomicAdd(&hist[b], 1u);
            ent[k] = (u << 9) | (v & (BSZ - 1u));
            ebr[k] = (b << 16) | r;            // b<391 (9b), r<8192 (13b)
        }
    }
    __syncthreads();

    // exclusive block scan of hist -> basel (NB=391 <= BINT)
    unsigned v0 = (tid < NB) ? hist[tid] : 0u;
    scan[tid] = v0;
    __syncthreads();
    for (int off = 1; off < BINT; off <<= 1) {
        unsigned mine = scan[tid];
        unsigned add  = (tid >= off) ? scan[tid - off] : 0u;
        __syncthreads();
        scan[tid] = mine + add;
        __syncthreads();
    }
    if (tid < NB) basel[tid] = scan[tid] - v0;
    __syncthreads();

#pragma unroll
    for (int k = 0; k < EPT; ++k) {
        if (ent[k] != 0xFFFFFFFFu)
            sorted[basel[ebr[k] >> 16] + (ebr[k] & 0xFFFFu)] = ent[k];
    }

    // reserve 8-aligned (32 B) global segments
    if (tid < NB) {
        unsigned c = hist[tid];
        unsigned p = (c + 7u) & ~7u;
        pcnt[tid]  = p;
        gbase[tid] = p ? atomicAdd(&cursor[tid], p) : 0u;
    }
    __syncthreads();

    // copy out: wave w handles buckets w, w+16, ... (full-sector stores)
    const int wave = tid >> 6, lane = tid & 63;
    for (int b = wave; b < NB; b += BINT / 64) {
        unsigned c = hist[b], p = pcnt[b], gb = gbase[b], lb = basel[b];
        if (p == 0u || gb + p > CAP) continue;   // overflow guard (never real)
        unsigned* dstp = binned + (size_t)b * CAP + gb;
        for (unsigned j = lane; j < p; j += 64)
            dstp[j] = (j < c) ? sorted[lb + j] : TRASH;
    }
}

// Per-bucket in-place LDS counting sort by local node; histogram = in-degree.
// Writes: binned (sorted pure-src), offs[b][0..256], dinv, p.
__global__ __launch_bounds__(ST) void
k15_sort(unsigned* __restrict__ binned, const unsigned* __restrict__ cursor,
         unsigned* __restrict__ offs, const float* __restrict__ x,
         float* __restrict__ dinv, float* __restrict__ p) {
    __shared__ unsigned hist[258];     // counts per local (256 = trash)
    __shared__ unsigned lofs[258];     // exclusive scan
    __shared__ unsigned scanws[512];
    __shared__ unsigned sortd[CAP];
    const int b = blockIdx.x, tid = threadIdx.x;
    if (tid < 258) hist[tid] = 0u;
    __syncthreads();
    unsigned m = cursor[b]; if (m > CAP) m = 0u;   // replay-safe
    unsigned* eb = binned + (size_t)b * CAP;

    unsigned ent[SIT], rnk[SIT];
#pragma unroll
    for (int kk = 0; kk < SIT; ++kk) {
        unsigned j = (unsigned)tid + kk * ST;
        if (j < m) {
            unsigned e = eb[j];
            unsigned l = min(e & 511u, TRASH);
            rnk[kk] = atomicAdd(&hist[l], 1u);
            ent[kk] = e;
        }
    }
    __syncthreads();

    // exclusive scan of hist[0..257] (257 bins used)
    unsigned v0 = (tid < 258) ? hist[tid] : 0u;
    if (tid < 512) scanws[tid] = (tid < 258) ? v0 : 0u;
    __syncthreads();
    for (int off = 1; off < 512; off <<= 1) {
        unsigned mine = 0u, add = 0u;
        if (tid < 512) { mine = scanws[tid]; add = (tid >= off) ? scanws[tid - off] : 0u; }
        __syncthreads();
        if (tid < 512) scanws[tid] = mine + add;
        __syncthreads();
    }
    if (tid < 258) lofs[tid] = scanws[tid] - v0;
    __syncthreads();

    // scatter into LDS sorted buffer (store pure src)
#pragma unroll
    for (int kk = 0; kk < SIT; ++kk) {
        unsigned j = (unsigned)tid + kk * ST;
        if (j < m) {
            unsigned e = ent[kk];
            unsigned l = min(e & 511u, TRASH);
            sortd[lofs[l] + rnk[kk]] = e >> 9;
        }
    }
    __syncthreads();

    // in-place write back (all reads done), plus offsets / dinv / p
    for (unsigned j = tid; j < m; j += ST)
        eb[j] = sortd[j];
    if (tid < 257) offs[(size_t)b * OSTR + tid] = lofs[tid];
    if (tid < BSZ) {
        int g = b * BSZ + tid;
        if (g < N_NODES) {
            float di = rsqrtf(1.0f + (float)hist[tid]);  // +1 self-loop
            dinv[g] = di;
            p[g] = di * x[g];
        }
    }
}

// layer-1 run-scan gather + fused MLP -> q = dinv * t
__global__ __launch_bounds__(GBT) void
k3_gather(const unsigned* __restrict__ binned, const unsigned* __restrict__ offs,
          const float* __restrict__ x, const float* __restrict__ dinv,
          const float* __restrict__ p,
          const float* __restrict__ W1, const float* __restrict__ b1,
          const float* __restrict__ W2, float* __restrict__ q) {
    int g = blockIdx.x * GBT + threadIdx.x;
    if (g >= N_NODES) return;
    int b = g >> BSH, l = g & (BSZ - 1);
    unsigned st = min(offs[(size_t)b * OSTR + l],     (unsigned)CAP);   // replay-safe
    unsigned en = min(offs[(size_t)b * OSTR + l + 1], (unsigned)CAP);
    if (en < st) en = st;
    const unsigned* eb = binned + (size_t)b * CAP;
    float acc = 0.0f;
    unsigned j = st;
    for (; j + 4 <= en; j += 4) {
        unsigned u0 = min(eb[j],     NM1);
        unsigned u1 = min(eb[j + 1], NM1);
        unsigned u2 = min(eb[j + 2], NM1);
        unsigned u3 = min(eb[j + 3], NM1);
        acc += p[u0] + p[u1] + p[u2] + p[u3];
    }
    for (; j < en; ++j) acc += p[min(eb[j], NM1)];
    float di = dinv[g];
    float s = di * (acc + di * x[g]);
    float t0 = 0.0f, t1 = 0.0f;
#pragma unroll
    for (int k = 0; k < 16; ++k) {
        float h = fmaxf(fmaf(s, W1[k], b1[k]), 0.0f);
        t0 = fmaf(h, W2[2 * k], t0);
        t1 = fmaf(h, W2[2 * k + 1], t1);
    }
    q[2 * g]     = di * t0;
    q[2 * g + 1] = di * t1;
}

// layer-2 run-scan gather -> out
__global__ __launch_bounds__(GBT) void
k4_gather(const unsigned* __restrict__ binned, const unsigned* __restrict__ offs,
          const float* __restrict__ dinv, const float* __restrict__ q,
          const float* __restrict__ b2, float* __restrict__ out) {
    int g = blockIdx.x * GBT + threadIdx.x;
    if (g >= N_NODES) return;
    int b = g >> BSH, l = g & (BSZ - 1);
    unsigned st = min(offs[(size_t)b * OSTR + l],     (unsigned)CAP);   // replay-safe
    unsigned en = min(offs[(size_t)b * OSTR + l + 1], (unsigned)CAP);
    if (en < st) en = st;
    const unsigned* eb = binned + (size_t)b * CAP;
    const float2* __restrict__ q2 = (const float2*)q;
    float a0 = 0.0f, a1 = 0.0f;
    unsigned j = st;
    for (; j + 4 <= en; j += 4) {
        float2 v0 = q2[min(eb[j],     NM1)];
        float2 v1 = q2[min(eb[j + 1], NM1)];
        float2 v2 = q2[min(eb[j + 2], NM1)];
        float2 v3 = q2[min(eb[j + 3], NM1)];
        a0 += v0.x + v1.x + v2.x + v3.x;
        a1 += v0.y + v1.y + v2.y + v3.y;
    }
    for (; j < en; ++j) {
        float2 v = q2[min(eb[j], NM1)];
        a0 += v.x; a1 += v.y;
    }
    float di = dinv[g];
    float2 o;
    o.x = fmaf(di, a0 + q[2 * g],     b2[0]);
    o.y = fmaf(di, a1 + q[2 * g + 1], b2[1]);
    ((float2*)out)[g] = o;
}

// ---- legacy atomic-scatter path (fallback if ws too small) -----------------
__global__ void k_init_deg(unsigned* __restrict__ degc, int n) {
    int i = blockIdx.x * blockDim.x + threadIdx.x;
    if (i < n) degc[i] = 1u;
}
__global__ void k_count_deg(const int* __restrict__ dst, unsigned* __restrict__ degc, int ne) {
    int stride = gridDim.x * blockDim.x;
    for (int i = blockIdx.x * blockDim.x + threadIdx.x; i < ne; i += stride)
        atomicAdd(&degc[dst[i]], 1u);
}
__global__ void k_dinv_selfloop(const float* __restrict__ x, const unsigned* __restrict__ degc,
                                float* __restrict__ dinv, float* __restrict__ s, int n) {
    int i = blockIdx.x * blockDim.x + threadIdx.x;
    if (i < n) {
        float di = rsqrtf((float)degc[i]);
        dinv[i] = di;
        s[i] = di * di * x[i];
    }
}
__global__ void k_scatter_s(const int* __restrict__ src, const int* __restrict__ dst,
                            const float* __restrict__ x, const float* __restrict__ dinv,
                            float* __restrict__ s, int ne) {
    int stride = gridDim.x * blockDim.x;
    for (int i = blockIdx.x * blockDim.x + threadIdx.x; i < ne; i += stride) {
        int u = src[i], v = dst[i];
        unsafeAtomicAdd(&s[v], dinv[u] * dinv[v] * x[u]);
    }
}
__global__ void k_node_g(const float* __restrict__ s, const float* __restrict__ dinv,
                         const float* __restrict__ W1, const float* __restrict__ b1,
                         const float* __restrict__ W2, const float* __restrict__ b2,
                         float* __restrict__ t, float* __restrict__ out, int n) {
    int i = blockIdx.x * blockDim.x + threadIdx.x;
    if (i < n) {
        float si = s[i];
        float t0 = 0.0f, t1 = 0.0f;
#pragma unroll
        for (int k = 0; k < 16; ++k) {
            float h = fmaxf(fmaf(si, W1[k], b1[k]), 0.0f);
            t0 = fmaf(h, W2[2 * k], t0);
            t1 = fmaf(h, W2[2 * k + 1], t1);
        }
        t[2 * i] = t0; t[2 * i + 1] = t1;
        float d2 = dinv[i] * dinv[i];
        out[2 * i]     = fmaf(d2, t0, b2[0]);
        out[2 * i + 1] = fmaf(d2, t1, b2[1]);
    }
}
__global__ void k_scatter_out(const int* __restrict__ src, const int* __restrict__ dst,
                              const float* __restrict__ dinv, const float* __restrict__ t,
                              float* __restrict__ out, int ne) {
    int stride = gridDim.x * blockDim.x;
    const float2* __restrict__ t2 = (const float2*)t;
    for (int i = blockIdx.x * blockDim.x + threadIdx.x; i < ne; i += stride) {
        int u = src[i], v = dst[i];
        float nrm = dinv[u] * dinv[v];
        float2 tu = t2[u];
        unsafeAtomicAdd(&out[2 * v],     nrm * tu.x);
        unsafeAtomicAdd(&out[2 * v + 1], nrm * tu.y);
    }
}

extern "C" void kernel_launch(void* const* d_in, const int* in_sizes, int n_in,
                              void* d_out, int out_size, void* d_ws, size_t ws_size,
                              hipStream_t stream) {
    const float* x  = (const float*)d_in[0];
    const int*   ei = (const int*)d_in[1];   // int32 [2, E]
    const float* W1 = (const float*)d_in[2];
    const float* b1 = (const float*)d_in[3];
    const float* W2 = (const float*)d_in[4];
    const float* b2 = (const float*)d_in[5];
    float*       out = (float*)d_out;

    const int* src = ei;
    const int* dst = ei + N_EDGES;

    // ws layout (4B units):
    // cursor[512] | dinv[N] | p[N] | q[2N] | offs[NB*257 pad to 100488] | binned[NB*CAP]
    float* base = (float*)d_ws;
    unsigned* cursor = (unsigned*)d_ws;
    float* dinv = base + 512;
    float* p    = base + 512 + N_NODES;
    float* q    = base + 512 + 2 * N_NODES;
    unsigned* offs = (unsigned*)(base + 512 + 4 * N_NODES);
    unsigned* binned = offs + 100488;                      // NB*257=100487, +1 pad
    const size_t NEEDED = ((size_t)512 + 4 * N_NODES + 100488
                           + (size_t)NB * CAP) * 4;        // ~18.5 MB

    if (ws_size >= NEEDED) {
        const int nbin_blocks = (N_EDGES + CHUNK - 1) / CHUNK;   // 391
        const int gath_blocks = (N_NODES + GBT - 1) / GBT;       // 782
        k0_zero<<<2, 256, 0, stream>>>(cursor);
        k1_bin<<<nbin_blocks, BINT, 0, stream>>>(src, dst, cursor, binned, N_EDGES);
        k15_sort<<<NB, ST, 0, stream>>>(binned, cursor, offs, x, dinv, p);
        k3_gather<<<gath_blocks, GBT, 0, stream>>>(binned, offs, x, dinv, p,
                                                   W1, b1, W2, q);
        k4_gather<<<gath_blocks, GBT, 0, stream>>>(binned, offs, dinv, q, b2, out);
    } else {
        // legacy atomic-scatter path
        unsigned* degc = (unsigned*)d_ws;
        float* ldinv = base + N_NODES;
        float* s     = base + 2 * N_NODES;
        float* t     = base + 3 * N_NODES;
        const int BLK = 256;
        const int node_grid = (N_NODES + BLK - 1) / BLK;
        const int edge_grid = 2048;
        k_init_deg<<<node_grid, BLK, 0, stream>>>(degc, N_NODES);
        k_count_deg<<<edge_grid, BLK, 0, stream>>>(dst, degc, N_EDGES);
        k_dinv_selfloop<<<node_grid, BLK, 0, stream>>>(x, degc, ldinv, s, N_NODES);
        k_scatter_s<<<edge_grid, BLK, 0, stream>>>(src, dst, x, ldinv, s, N_EDGES);
        k_node_g<<<node_grid, BLK, 0, stream>>>(s, ldinv, W1, b1, W2, b2, t, out, N_NODES);
        k_scatter_out<<<edge_grid, BLK, 0, stream>>>(src, dst, ldinv, t, out, N_EDGES);
    }
}

// Round 14
// 149.324 us; speedup vs baseline: 1.3210x; 1.0233x over previous
//
#include <hip/hip_runtime.h>

#define N_NODES 100000
#define N_EDGES 3200000

// ---- bucket parameters -----------------------------------------------------
#define BSH   8                    // log2(nodes per bucket)
#define BSZ   256                  // nodes per bucket
#define NB    391                  // ceil(N_NODES / BSZ)
#define CAP   10560                // per-bucket capacity (mult of 8; <= 11*1024)
#define CHUNK 8192                 // edges per binning block
#define BINT  1024                 // threads per binning block
#define EPT   (CHUNK / BINT)       // 8 edges per thread
#define ST    1024                 // threads per sort block
#define SIT   11                   // ceil(CAP / ST) load slots per sort thread
#define GBT   128                  // threads per gather block (2 waves)
#define TRASH 256u                 // local slot 256 = discard
#define NM1   ((unsigned)(N_NODES - 1))
#define OSTR  257                  // offs stride per bucket (l=0..256)

// ---------------------------------------------------------------------------
// Algebra (x is [N,1]):
//   p[u]   = dinv[u] * x[u]
//   s[v]   = dinv[v] * (sum_in p[u] + dinv[v]*x[v])
//   t[v]   = relu(s[v]*W1 + b1) @ W2          (2-vector)
//   q[v]   = dinv[v] * t[v]
//   out[v] = dinv[v] * (sum_in q[u] + q[v]) + b2
//
// R4:  device f32 atomics are memory-side (~20 G/s) -> gather, not scatter.
// R6:  scattered 4B binning writes -> 5x write amp -> LDS counting sort in k1.
// R9-R11: LDS-atomic bucket-gathers latency-bound -> k15 per-bucket sort,
//      atomic-free run-scan gathers (R13: 197 -> 153 us).
// R13: profile blinded by harness ws-poison fills; remaining known fat =
//      Hillis-Steele scans (20 barriers each in k1/k15). Fix: two-level
//      wave-shuffle scans (3 barriers); skip TRASH-tail writeback in k15.
// binned after k1: (src<<9)|local with TRASH pads; after k15: pure src,
// runs delimited by offs[b][l], pads (stale k1 format) beyond lofs[256].
// ---------------------------------------------------------------------------

__global__ void k0_zero(unsigned* __restrict__ cursor) {
    int i = blockIdx.x * blockDim.x + threadIdx.x;
    if (i < NB) cursor[i] = 0u;
}

__global__ __launch_bounds__(BINT) void
k1_bin(const int* __restrict__ src, const int* __restrict__ dst,
       unsigned* __restrict__ cursor, unsigned* __restrict__ binned, int ne) {
    __shared__ unsigned hist[NB];      // per-bucket count (rank source)
    __shared__ unsigned basel[NB];     // exclusive prefix into sorted[]
    __shared__ unsigned gbase[NB];     // global segment base per bucket
    __shared__ unsigned pcnt[NB];      // padded count per bucket
    __shared__ unsigned sorted[CHUNK]; // bucket-sorted entries
    __shared__ unsigned wsum[8];       // per-wave scan sums
    const int tid = threadIdx.x;
    const int b0  = blockIdx.x * CHUNK;
    const int end = min(b0 + CHUNK, ne);

    for (int i = tid; i < NB; i += BINT) hist[i] = 0u;
    __syncthreads();

    unsigned ent[EPT], ebr[EPT];
#pragma unroll
    for (int k = 0; k < EPT; ++k) {
        int i = b0 + tid + k * BINT;
        ent[k] = 0xFFFFFFFFu;
        if (i < end) {
            unsigned v = (unsigned)dst[i];
            unsigned u = (unsigned)src[i];
            unsigned b = v >> BSH;
            unsigned r = atomicAdd(&hist[b], 1u);
            ent[k] = (u << 9) | (v & (BSZ - 1u));
            ebr[k] = (b << 16) | r;            // b<391 (9b), r<8192 (13b)
        }
    }
    __syncthreads();

    // two-level wave-shuffle exclusive scan of hist[0..NB) -> basel
    {
        const int w = tid >> 6, lane = tid & 63;
        unsigned v = 0u, sc = 0u;
        if (tid < 448) {                       // waves 0..6 cover NB=391
            v = (tid < NB) ? hist[tid] : 0u;
            sc = v;
#pragma unroll
            for (int off = 1; off < 64; off <<= 1) {
                unsigned n = __shfl_up(sc, off, 64);
                if (lane >= off) sc += n;
            }
            if (lane == 63) wsum[w] = sc;      // inclusive wave total
        }
        __syncthreads();
        if (tid < NB) {
            unsigned wo = 0u;
            for (int i = 0; i < w; ++i) wo += wsum[i];
            basel[tid] = wo + sc - v;          // exclusive
        }
    }
    __syncthreads();

#pragma unroll
    for (int k = 0; k < EPT; ++k) {
        if (ent[k] != 0xFFFFFFFFu)
            sorted[basel[ebr[k] >> 16] + (ebr[k] & 0xFFFFu)] = ent[k];
    }

    // reserve 8-aligned (32 B) global segments
    if (tid < NB) {
        unsigned c = hist[tid];
        unsigned p = (c + 7u) & ~7u;
        pcnt[tid]  = p;
        gbase[tid] = p ? atomicAdd(&cursor[tid], p) : 0u;
    }
    __syncthreads();

    // copy out: wave w handles buckets w, w+16, ... (full-sector stores)
    const int wave = tid >> 6, lane = tid & 63;
    for (int b = wave; b < NB; b += BINT / 64) {
        unsigned c = hist[b], p = pcnt[b], gb = gbase[b], lb = basel[b];
        if (p == 0u || gb + p > CAP) continue;   // overflow guard (never real)
        unsigned* dstp = binned + (size_t)b * CAP + gb;
        for (unsigned j = lane; j < p; j += 64)
            dstp[j] = (j < c) ? sorted[lb + j] : TRASH;
    }
}

// Per-bucket in-place LDS counting sort by local node; histogram = in-degree.
// Writes: binned (sorted pure-src, payload only), offs[b][0..256], dinv, p.
__global__ __launch_bounds__(ST) void
k15_sort(unsigned* __restrict__ binned, const unsigned* __restrict__ cursor,
         unsigned* __restrict__ offs, const float* __restrict__ x,
         float* __restrict__ dinv, float* __restrict__ p) {
    __shared__ unsigned hist[258];     // counts per local (256 = trash)
    __shared__ unsigned lofs[258];     // exclusive scan
    __shared__ unsigned wsum[8];
    __shared__ unsigned sortd[CAP];
    const int b = blockIdx.x, tid = threadIdx.x;
    if (tid < 258) hist[tid] = 0u;
    __syncthreads();
    unsigned m = cursor[b]; if (m > CAP) m = 0u;   // replay-safe
    unsigned* eb = binned + (size_t)b * CAP;

    unsigned ent[SIT], rnk[SIT];
#pragma unroll
    for (int kk = 0; kk < SIT; ++kk) {
        unsigned j = (unsigned)tid + kk * ST;
        if (j < m) {
            unsigned e = eb[j];
            unsigned l = min(e & 511u, TRASH);
            rnk[kk] = atomicAdd(&hist[l], 1u);
            ent[kk] = e;
        }
    }
    __syncthreads();

    // two-level wave-shuffle exclusive scan of hist[0..258) -> lofs
    {
        const int w = tid >> 6, lane = tid & 63;
        unsigned v = 0u, sc = 0u;
        if (tid < 320) {                       // waves 0..4 cover 258
            v = (tid < 258) ? hist[tid] : 0u;
            sc = v;
#pragma unroll
            for (int off = 1; off < 64; off <<= 1) {
                unsigned n = __shfl_up(sc, off, 64);
                if (lane >= off) sc += n;
            }
            if (lane == 63) wsum[w] = sc;
        }
        __syncthreads();
        if (tid < 258) {
            unsigned wo = 0u;
            for (int i = 0; i < w; ++i) wo += wsum[i];
            lofs[tid] = wo + sc - v;
        }
    }
    __syncthreads();

    // scatter into LDS sorted buffer (store pure src)
#pragma unroll
    for (int kk = 0; kk < SIT; ++kk) {
        unsigned j = (unsigned)tid + kk * ST;
        if (j < m) {
            unsigned e = ent[kk];
            unsigned l = min(e & 511u, TRASH);
            sortd[lofs[l] + rnk[kk]] = e >> 9;
        }
    }
    __syncthreads();

    // write back payload only (skip compacted TRASH tail), offs / dinv / p
    unsigned mreal = min(lofs[256], m);
    for (unsigned j = tid; j < mreal; j += ST)
        eb[j] = sortd[j];
    if (tid < 257) offs[(size_t)b * OSTR + tid] = lofs[tid];
    if (tid < BSZ) {
        int g = b * BSZ + tid;
        if (g < N_NODES) {
            float di = rsqrtf(1.0f + (float)hist[tid]);  // +1 self-loop
            dinv[g] = di;
            p[g] = di * x[g];
        }
    }
}

// layer-1 run-scan gather + fused MLP -> q = dinv * t
__global__ __launch_bounds__(GBT) void
k3_gather(const unsigned* __restrict__ binned, const unsigned* __restrict__ offs,
          const float* __restrict__ x, const float* __restrict__ dinv,
          const float* __restrict__ p,
          const float* __restrict__ W1, const float* __restrict__ b1,
          const float* __restrict__ W2, float* __restrict__ q) {
    int g = blockIdx.x * GBT + threadIdx.x;
    if (g >= N_NODES) return;
    int b = g >> BSH, l = g & (BSZ - 1);
    unsigned st = min(offs[(size_t)b * OSTR + l],     (unsigned)CAP);   // replay-safe
    unsigned en = min(offs[(size_t)b * OSTR + l + 1], (unsigned)CAP);
    if (en < st) en = st;
    const unsigned* eb = binned + (size_t)b * CAP;
    float acc = 0.0f;
    unsigned j = st;
    for (; j + 4 <= en; j += 4) {
        unsigned u0 = min(eb[j],     NM1);
        unsigned u1 = min(eb[j + 1], NM1);
        unsigned u2 = min(eb[j + 2], NM1);
        unsigned u3 = min(eb[j + 3], NM1);
        acc += p[u0] + p[u1] + p[u2] + p[u3];
    }
    for (; j < en; ++j) acc += p[min(eb[j], NM1)];
    float di = dinv[g];
    float s = di * (acc + di * x[g]);
    float t0 = 0.0f, t1 = 0.0f;
#pragma unroll
    for (int k = 0; k < 16; ++k) {
        float h = fmaxf(fmaf(s, W1[k], b1[k]), 0.0f);
        t0 = fmaf(h, W2[2 * k], t0);
        t1 = fmaf(h, W2[2 * k + 1], t1);
    }
    q[2 * g]     = di * t0;
    q[2 * g + 1] = di * t1;
}

// layer-2 run-scan gather -> out
__global__ __launch_bounds__(GBT) void
k4_gather(const unsigned* __restrict__ binned, const unsigned* __restrict__ offs,
          const float* __restrict__ dinv, const float* __restrict__ q,
          const float* __restrict__ b2, float* __restrict__ out) {
    int g = blockIdx.x * GBT + threadIdx.x;
    if (g >= N_NODES) return;
    int b = g >> BSH, l = g & (BSZ - 1);
    unsigned st = min(offs[(size_t)b * OSTR + l],     (unsigned)CAP);   // replay-safe
    unsigned en = min(offs[(size_t)b * OSTR + l + 1], (unsigned)CAP);
    if (en < st) en = st;
    const unsigned* eb = binned + (size_t)b * CAP;
    const float2* __restrict__ q2 = (const float2*)q;
    float a0 = 0.0f, a1 = 0.0f;
    unsigned j = st;
    for (; j + 4 <= en; j += 4) {
        float2 v0 = q2[min(eb[j],     NM1)];
        float2 v1 = q2[min(eb[j + 1], NM1)];
        float2 v2 = q2[min(eb[j + 2], NM1)];
        float2 v3 = q2[min(eb[j + 3], NM1)];
        a0 += v0.x + v1.x + v2.x + v3.x;
        a1 += v0.y + v1.y + v2.y + v3.y;
    }
    for (; j < en; ++j) {
        float2 v = q2[min(eb[j], NM1)];
        a0 += v.x; a1 += v.y;
    }
    float di = dinv[g];
    float2 o;
    o.x = fmaf(di, a0 + q[2 * g],     b2[0]);
    o.y = fmaf(di, a1 + q[2 * g + 1], b2[1]);
    ((float2*)out)[g] = o;
}

// ---- legacy atomic-scatter path (fallback if ws too small) -----------------
__global__ void k_init_deg(unsigned* __restrict__ degc, int n) {
    int i = blockIdx.x * blockDim.x + threadIdx.x;
    if (i < n) degc[i] = 1u;
}
__global__ void k_count_deg(const int* __restrict__ dst, unsigned* __restrict__ degc, int ne) {
    int stride = gridDim.x * blockDim.x;
    for (int i = blockIdx.x * blockDim.x + threadIdx.x; i < ne; i += stride)
        atomicAdd(&degc[dst[i]], 1u);
}
__global__ void k_dinv_selfloop(const float* __restrict__ x, const unsigned* __restrict__ degc,
                                float* __restrict__ dinv, float* __restrict__ s, int n) {
    int i = blockIdx.x * blockDim.x + threadIdx.x;
    if (i < n) {
        float di = rsqrtf((float)degc[i]);
        dinv[i] = di;
        s[i] = di * di * x[i];
    }
}
__global__ void k_scatter_s(const int* __restrict__ src, const int* __restrict__ dst,
                            const float* __restrict__ x, const float* __restrict__ dinv,
                            float* __restrict__ s, int ne) {
    int stride = gridDim.x * blockDim.x;
    for (int i = blockIdx.x * blockDim.x + threadIdx.x; i < ne; i += stride) {
        int u = src[i], v = dst[i];
        unsafeAtomicAdd(&s[v], dinv[u] * dinv[v] * x[u]);
    }
}
__global__ void k_node_g(const float* __restrict__ s, const float* __restrict__ dinv,
                         const float* __restrict__ W1, const float* __restrict__ b1,
                         const float* __restrict__ W2, const float* __restrict__ b2,
                         float* __restrict__ t, float* __restrict__ out, int n) {
    int i = blockIdx.x * blockDim.x + threadIdx.x;
    if (i < n) {
        float si = s[i];
        float t0 = 0.0f, t1 = 0.0f;
#pragma unroll
        for (int k = 0; k < 16; ++k) {
            float h = fmaxf(fmaf(si, W1[k], b1[k]), 0.0f);
            t0 = fmaf(h, W2[2 * k], t0);
            t1 = fmaf(h, W2[2 * k + 1], t1);
        }
        t[2 * i] = t0; t[2 * i + 1] = t1;
        float d2 = dinv[i] * dinv[i];
        out[2 * i]     = fmaf(d2, t0, b2[0]);
        out[2 * i + 1] = fmaf(d2, t1, b2[1]);
    }
}
__global__ void k_scatter_out(const int* __restrict__ src, const int* __restrict__ dst,
                              const float* __restrict__ dinv, const float* __restrict__ t,
                              float* __restrict__ out, int ne) {
    int stride = gridDim.x * blockDim.x;
    const float2* __restrict__ t2 = (const float2*)t;
    for (int i = blockIdx.x * blockDim.x + threadIdx.x; i < ne; i += stride) {
        int u = src[i], v = dst[i];
        float nrm = dinv[u] * dinv[v];
        float2 tu = t2[u];
        unsafeAtomicAdd(&out[2 * v],     nrm * tu.x);
        unsafeAtomicAdd(&out[2 * v + 1], nrm * tu.y);
    }
}

extern "C" void kernel_launch(void* const* d_in, const int* in_sizes, int n_in,
                              void* d_out, int out_size, void* d_ws, size_t ws_size,
                              hipStream_t stream) {
    const float* x  = (const float*)d_in[0];
    const int*   ei = (const int*)d_in[1];   // int32 [2, E]
    const float* W1 = (const float*)d_in[2];
    const float* b1 = (const float*)d_in[3];
    const float* W2 = (const float*)d_in[4];
    const float* b2 = (const float*)d_in[5];
    float*       out = (float*)d_out;

    const int* src = ei;
    const int* dst = ei + N_EDGES;

    // ws layout (4B units):
    // cursor[512] | dinv[N] | p[N] | q[2N] | offs[NB*257 pad to 100488] | binned[NB*CAP]
    float* base = (float*)d_ws;
    unsigned* cursor = (unsigned*)d_ws;
    float* dinv = base + 512;
    float* p    = base + 512 + N_NODES;
    float* q    = base + 512 + 2 * N_NODES;
    unsigned* offs = (unsigned*)(base + 512 + 4 * N_NODES);
    unsigned* binned = offs + 100488;                      // NB*257=100487, +1 pad
    const size_t NEEDED = ((size_t)512 + 4 * N_NODES + 100488
                           + (size_t)NB * CAP) * 4;        // ~18.5 MB

    if (ws_size >= NEEDED) {
        const int nbin_blocks = (N_EDGES + CHUNK - 1) / CHUNK;   // 391
        const int gath_blocks = (N_NODES + GBT - 1) / GBT;       // 782
        k0_zero<<<2, 256, 0, stream>>>(cursor);
        k1_bin<<<nbin_blocks, BINT, 0, stream>>>(src, dst, cursor, binned, N_EDGES);
        k15_sort<<<NB, ST, 0, stream>>>(binned, cursor, offs, x, dinv, p);
        k3_gather<<<gath_blocks, GBT, 0, stream>>>(binned, offs, x, dinv, p,
                                                   W1, b1, W2, q);
        k4_gather<<<gath_blocks, GBT, 0, stream>>>(binned, offs, dinv, q, b2, out);
    } else {
        // legacy atomic-scatter path
        unsigned* degc = (unsigned*)d_ws;
        float* ldinv = base + N_NODES;
        float* s     = base + 2 * N_NODES;
        float* t     = base + 3 * N_NODES;
        const int BLK = 256;
        const int node_grid = (N_NODES + BLK - 1) / BLK;
        const int edge_grid = 2048;
        k_init_deg<<<node_grid, BLK, 0, stream>>>(degc, N_NODES);
        k_count_deg<<<edge_grid, BLK, 0, stream>>>(dst, degc, N_EDGES);
        k_dinv_selfloop<<<node_grid, BLK, 0, stream>>>(x, degc, ldinv, s, N_NODES);
        k_scatter_s<<<edge_grid, BLK, 0, stream>>>(src, dst, x, ldinv, s, N_EDGES);
        k_node_g<<<node_grid, BLK, 0, stream>>>(s, ldinv, W1, b1, W2, b2, t, out, N_NODES);
        k_scatter_out<<<edge_grid, BLK, 0, stream>>>(src, dst, ldinv, t, out, N_EDGES);
    }
}